// Round 3
// baseline (232.869 us; speedup 1.0000x reference)
//
#include <hip/hip_runtime.h>
#include <math.h>

// Dims (fixed by the problem)
#define B_SZ 2
#define L_SZ 384
#define D_SZ 384
#define S_SZ 384
#define BLK_ELEMS (L_SZ * D_SZ)        // 147456 per batch
#define TOT_ELEMS (B_SZ * L_SZ * D_SZ) // 294912

__device__ __forceinline__ float fexp2(float x) {
  return __builtin_amdgcn_exp2f(x);
}

__device__ __forceinline__ float softplus_f(float z) {
  return (z > 20.f) ? z : log1pf(__expf(z));
}

// ---------------------------------------------------------------------------
// DPP wave64 reduction -> full sum lands in lane 63. VALU pipe, no DS.
// (HW-verified in Round 1/2: absmax matched with this sequence.)
// ---------------------------------------------------------------------------
template <int CTRL, int RMASK>
__device__ __forceinline__ float dpp_add(float v) {
  int t = __builtin_amdgcn_update_dpp(0, __float_as_int(v), CTRL, RMASK, 0xF, true);
  return v + __int_as_float(t);
}
__device__ __forceinline__ float wave_reduce_lane63(float v) {
  v = dpp_add<0xB1, 0xF>(v);   // xor 1
  v = dpp_add<0x4E, 0xF>(v);   // xor 2
  v = dpp_add<0x141, 0xF>(v);  // row_half_mirror
  v = dpp_add<0x140, 0xF>(v);  // row_mirror -> per-row sums
  v = dpp_add<0x142, 0xA>(v);  // row_bcast15
  v = dpp_add<0x143, 0xC>(v);  // row_bcast31; lane63 = total
  return v;
}

// ---------------------------------------------------------------------------
// Dual NT-GEMM: O1[m,n] = (softplus?)(sum_k A[m,k]*W1[n,k] + b1[n])
//               O2[m,n] =             sum_k A[m,k]*W2[n,k]
// M=768, N=384, K=384. 32x32 tile, 128 threads (2 waves), 2x4 micro-tile.
// grid = 12 x 24 = 288 blocks (fills the 256 CUs; Round-2's 72 blocks did not).
// LDS k-major, leading dim padded to 36 so b64/b128 fragment reads stay
// aligned and bank-clean.
// ---------------------------------------------------------------------------
template <bool SP>
__global__ __launch_bounds__(128) void dual_gemm_nt(
    const float* __restrict__ A, const float* __restrict__ W1,
    const float* __restrict__ W2, const float* __restrict__ b1,
    float* __restrict__ O1, float* __restrict__ O2) {
  __shared__ float As[32][36];
  __shared__ float W1s[32][36];
  __shared__ float W2s[32][36];

  const int tid = threadIdx.x;
  const int tm = tid & 15;   // m micro index (2 rows)
  const int tn = tid >> 4;   // n micro index (4 cols), 0..7
  const int m0 = blockIdx.y * 32;
  const int n0 = blockIdx.x * 32;
  const int sm = tid >> 2;        // staging row 0..31
  const int sk = (tid & 3) * 4;   // staging k quad 0,4,8,12

  float4 ra[2], r1[2], r2[2];
  auto gload = [&](int kt) {
#pragma unroll
    for (int h = 0; h < 2; ++h) {
      const int off = kt + sk + 16 * h;
      ra[h] = *(const float4*)(A + (m0 + sm) * 384 + off);
      r1[h] = *(const float4*)(W1 + (n0 + sm) * 384 + off);
      r2[h] = *(const float4*)(W2 + (n0 + sm) * 384 + off);
    }
  };

  float acc1[2][4] = {{0.f}};
  float acc2[2][4] = {{0.f}};

  gload(0);
  for (int kt = 0; kt < 384; kt += 32) {
    __syncthreads();  // previous chunk's compute done; safe to overwrite LDS
#pragma unroll
    for (int h = 0; h < 2; ++h) {
      const int kb = sk + 16 * h;
      As[kb + 0][sm] = ra[h].x; As[kb + 1][sm] = ra[h].y;
      As[kb + 2][sm] = ra[h].z; As[kb + 3][sm] = ra[h].w;
      W1s[kb + 0][sm] = r1[h].x; W1s[kb + 1][sm] = r1[h].y;
      W1s[kb + 2][sm] = r1[h].z; W1s[kb + 3][sm] = r1[h].w;
      W2s[kb + 0][sm] = r2[h].x; W2s[kb + 1][sm] = r2[h].y;
      W2s[kb + 2][sm] = r2[h].z; W2s[kb + 3][sm] = r2[h].w;
    }
    __syncthreads();
    if (kt + 32 < 384) gload(kt + 32);  // overlaps compute below
#pragma unroll
    for (int k = 0; k < 32; ++k) {
      const float2 av = *(const float2*)&As[k][2 * tm];
      const float4 w1 = *(const float4*)&W1s[k][4 * tn];
      const float4 w2 = *(const float4*)&W2s[k][4 * tn];
      const float a[2] = {av.x, av.y};
      const float x1[4] = {w1.x, w1.y, w1.z, w1.w};
      const float x2[4] = {w2.x, w2.y, w2.z, w2.w};
#pragma unroll
      for (int r = 0; r < 2; ++r) {
#pragma unroll
        for (int c = 0; c < 4; ++c) {
          acc1[r][c] = fmaf(a[r], x1[c], acc1[r][c]);
          acc2[r][c] = fmaf(a[r], x2[c], acc2[r][c]);
        }
      }
    }
  }

  const int nb = n0 + 4 * tn;
#pragma unroll
  for (int r = 0; r < 2; ++r) {
    const int row = m0 + 2 * tm + r;
    float4 o1, o2;
    float* o1p = &o1.x;
    float* o2p = &o2.x;
    if constexpr (SP) {
#pragma unroll
      for (int c = 0; c < 4; ++c)
        o1p[c] = softplus_f(acc1[r][c] + b1[nb + c]);
    } else {
#pragma unroll
      for (int c = 0; c < 4; ++c) o1p[c] = acc1[r][c];
    }
#pragma unroll
    for (int c = 0; c < 4; ++c) o2p[c] = acc2[r][c];
    *(float4*)(O1 + row * 384 + nb) = o1;
    *(float4*)(O2 + row * 384 + nb) = o2;
  }
}

// ---------------------------------------------------------------------------
// Causal depthwise conv (k=4, left pad 3) + bias + SiLU -> u[b,l,i]
// ---------------------------------------------------------------------------
__global__ __launch_bounds__(256) void conv_silu_kernel(
    const float* __restrict__ x, const float* __restrict__ cw,
    const float* __restrict__ cb, float* __restrict__ u) {
  const int idx = blockIdx.x * 256 + threadIdx.x;  // over B*L*D
  const int i = idx % D_SZ;
  const int l = (idx / D_SZ) % L_SZ;
  const int b = idx / BLK_ELEMS;
  float acc = cb[i];
#pragma unroll
  for (int t = 0; t < 4; t++) {
    const int ls = l - 3 + t;
    const float xv = (ls >= 0) ? x[(b * L_SZ + ls) * D_SZ + i] : 0.f;
    acc = fmaf(xv, cw[i * 4 + t], acc);
  }
  u[idx] = acc / (1.f + __expf(-acc));  // silu
}

// ---------------------------------------------------------------------------
// Selective scan v3: block = 3 waves = 3 consecutive i of the SAME batch
// (384 % 3 == 0 keeps batches block-aligned); grid = 256 = 1 block/CU.
// Cm rows are staged in double-buffered LDS chunks of 8 and shared by the
// 3 waves (3x less L2/L3 traffic than v2). State mapping j = 2*lane+128*t+e
// -> per-step C reads are three conflict-free ds_read_b64.
// ---------------------------------------------------------------------------
#define CH 8
#define NCHUNK (L_SZ / CH)  // 48

__global__ __launch_bounds__(192) void scan_kernel(
    const float* __restrict__ A_log, const float* __restrict__ Dp,
    const float* __restrict__ dt, const float* __restrict__ Bm,
    const float* __restrict__ Cm, const float* __restrict__ u,
    float* __restrict__ y) {
  __shared__ float Cs[2][CH][S_SZ];  // 24 KB

  const int tid = threadIdx.x;        // 0..191
  const int wv = tid >> 6;            // wave 0..2
  const int lane = tid & 63;
  const int sid = blockIdx.x * 3 + wv;  // scan id 0..767
  const int b = sid / D_SZ;             // uniform per block
  const int i = sid % D_SZ;

  // per-lane state slots: j = 2*lane + 128*t + e, t in 0..2, e in 0..1
  float a2[6], bw[6], h[6];
  {
    const float2* ar = (const float2*)(A_log + i * S_SZ);
    const float2* br = (const float2*)(Bm + (b * D_SZ + i) * S_SZ);
#pragma unroll
    for (int t = 0; t < 3; ++t) {
      const float2 av = ar[lane + 64 * t];
      const float2 bv = br[lane + 64 * t];
      a2[2 * t] = -__expf(av.x) * 1.4426950408889634f;
      a2[2 * t + 1] = -__expf(av.y) * 1.4426950408889634f;
      bw[2 * t] = bv.x;
      bw[2 * t + 1] = bv.y;
      h[2 * t] = 0.f;
      h[2 * t + 1] = 0.f;
    }
  }
  const float Di = Dp[i];

  const float* dtp = dt + b * BLK_ELEMS + i;
  const float* up = u + b * BLK_ELEMS + i;
  const float* cbase = Cm + b * BLK_ELEMS;  // uniform per block
  float* yp = y + b * BLK_ELEMS + i;

  float4 cr[4];  // cooperative staging regs: 192 thr x 4 float4 = 3072 floats
  auto stage_load = [&](int c) {
    const float* src = cbase + c * (CH * S_SZ);
#pragma unroll
    for (int s = 0; s < 4; ++s)
      cr[s] = *(const float4*)(src + tid * 4 + s * 768);
  };
  auto stage_write = [&](int p) {
    float* dst = &Cs[p][0][0];
#pragma unroll
    for (int s = 0; s < 4; ++s)
      *(float4*)(dst + tid * 4 + s * 768) = cr[s];
  };
  float dA[CH], uA[CH], dB[CH], uB[CH];
  auto load_du = [&](int c, float (&d)[CH], float (&uu)[CH]) {
    const int l0 = c * CH;
#pragma unroll
    for (int s = 0; s < CH; ++s) {
      d[s] = dtp[(l0 + s) * D_SZ];
      uu[s] = up[(l0 + s) * D_SZ];
    }
  };

  auto compute_chunk = [&](int c, int p, const float (&d)[CH],
                           const float (&uu)[CH]) {
    const int l0 = c * CH;
#pragma unroll
    for (int s = 0; s < CH; ++s) {
      const float dt_s = d[s], u_s = uu[s];
      const float dtu = dt_s * u_s;
      const float2* crow = (const float2*)&Cs[p][s][0];
      float acc = 0.f;
#pragma unroll
      for (int t = 0; t < 3; ++t) {
        const float2 cc = crow[lane + 64 * t];
        const float e0 = fexp2(dt_s * a2[2 * t]);
        const float e1 = fexp2(dt_s * a2[2 * t + 1]);
        h[2 * t] = fmaf(e0, h[2 * t], bw[2 * t] * dtu);
        h[2 * t + 1] = fmaf(e1, h[2 * t + 1], bw[2 * t + 1] * dtu);
        acc = fmaf(h[2 * t], cc.x, acc);
        acc = fmaf(h[2 * t + 1], cc.y, acc);
      }
      acc = wave_reduce_lane63(acc);
      if (lane == 63) yp[(l0 + s) * D_SZ] = fmaf(u_s, Di, acc);
    }
  };

  // prologue: chunk 0 into Cs[0]
  stage_load(0);
  load_du(0, dA, uA);
  stage_write(0);

  for (int it = 0; it < NCHUNK / 2; ++it) {
    const int c0 = 2 * it, c1 = 2 * it + 1;
    stage_load(c1);
    load_du(c1, dB, uB);
    __syncthreads();             // Cs[0] ready
    compute_chunk(c0, 0, dA, uA);
    __syncthreads();             // all waves done reading Cs[1] (chunk c1-2)
    stage_write(1);
    if (it + 1 < NCHUNK / 2) {
      stage_load(c0 + 2);
      load_du(c0 + 2, dA, uA);
    }
    __syncthreads();             // Cs[1] ready
    compute_chunk(c1, 1, dB, uB);
    __syncthreads();             // all waves done reading Cs[0]
    if (it + 1 < NCHUNK / 2) stage_write(0);
  }
}

extern "C" void kernel_launch(void* const* d_in, const int* in_sizes, int n_in,
                              void* d_out, int out_size, void* d_ws,
                              size_t ws_size, hipStream_t stream) {
  const float* x = (const float*)d_in[0];
  const float* A_log = (const float*)d_in[1];
  const float* D = (const float*)d_in[2];
  const float* dt_w = (const float*)d_in[3];
  const float* dt_b = (const float*)d_in[4];
  const float* B_w = (const float*)d_in[5];
  const float* C_w = (const float*)d_in[6];
  const float* conv_w = (const float*)d_in[7];
  const float* conv_b = (const float*)d_in[8];
  float* y = (float*)d_out;

  float* ws = (float*)d_ws;
  float* dt = ws;                    // 294912
  float* xdbl = ws + TOT_ELEMS;      // 294912
  float* Bm = ws + 2 * TOT_ELEMS;    // 294912
  float* Cm = ws + 3 * TOT_ELEMS;    // 294912
  float* u = ws + 4 * TOT_ELEMS;     // 294912  (total 5.9 MB)

  const dim3 gemm_grid(D_SZ / 32, (B_SZ * L_SZ) / 32);  // 12 x 24 = 288
  dual_gemm_nt<true><<<gemm_grid, 128, 0, stream>>>(x, dt_w, B_w, dt_b, dt, xdbl);
  dual_gemm_nt<false><<<gemm_grid, 128, 0, stream>>>(xdbl, B_w, C_w, nullptr, Bm, Cm);
  conv_silu_kernel<<<TOT_ELEMS / 256, 256, 0, stream>>>(x, conv_w, conv_b, u);
  scan_kernel<<<256, 192, 0, stream>>>(A_log, D, dt, Bm, Cm, u, y);
}

// Round 4
// 198.579 us; speedup vs baseline: 1.1727x; 1.1727x over previous
//
#include <hip/hip_runtime.h>
#include <math.h>

// Dims (fixed by the problem)
#define B_SZ 2
#define L_SZ 384
#define D_SZ 384
#define S_SZ 384
#define BLK_ELEMS (L_SZ * D_SZ)        // 147456 per batch
#define TOT_ELEMS (B_SZ * L_SZ * D_SZ) // 294912
#define LOG2E 1.4426950408889634f

__device__ __forceinline__ float fexp2(float x) {
  return __builtin_amdgcn_exp2f(x);
}

__device__ __forceinline__ float softplus_f(float z) {
  return (z > 20.f) ? z : log1pf(__expf(z));
}

// ---------------------------------------------------------------------------
// DPP wave64 reduction -> full sum lands in lane 63 (HW-verified R1-R3).
// ---------------------------------------------------------------------------
template <int CTRL, int RMASK>
__device__ __forceinline__ float dpp_add(float v) {
  int t = __builtin_amdgcn_update_dpp(0, __float_as_int(v), CTRL, RMASK, 0xF, true);
  return v + __int_as_float(t);
}
__device__ __forceinline__ float wave_reduce_lane63(float v) {
  v = dpp_add<0xB1, 0xF>(v);
  v = dpp_add<0x4E, 0xF>(v);
  v = dpp_add<0x141, 0xF>(v);
  v = dpp_add<0x140, 0xF>(v);
  v = dpp_add<0x142, 0xA>(v);
  v = dpp_add<0x143, 0xC>(v);
  return v;
}

// ---------------------------------------------------------------------------
// Dual NT-GEMM: O1[m,n] = (softplus?)(sum_k A[m,k]*W1[n,k] + b1[n])
//               O2[m,n] =             sum_k A[m,k]*W2[n,k]
// M=768, N=384, K=384. 32x32 tile, 256 thr, 2x2 micro, grid 288.
// k-major LDS (pad 34: 8B-aligned rows -> clean ds_read_b64 frags).
// Double-buffered LDS, ONE barrier per chunk; global prefetch regs are
// loaded a full iteration before their LDS write (latency covered by the
// 32-k compute). launch_bounds(256,4) -> 128-VGPR cap, no load-sinking.
// ---------------------------------------------------------------------------
template <bool SP>
__global__ __launch_bounds__(256, 4) void dual_gemm_nt(
    const float* __restrict__ A, const float* __restrict__ W1,
    const float* __restrict__ W2, const float* __restrict__ b1,
    float* __restrict__ O1, float* __restrict__ O2) {
  __shared__ float As[2][32][34];
  __shared__ float W1s[2][32][34];
  __shared__ float W2s[2][32][34];

  const int tid = threadIdx.x;
  const int tx = tid & 15;        // n micro (2 cols)
  const int ty = tid >> 4;        // m micro (2 rows)
  const int m0 = blockIdx.y * 32;
  const int n0 = blockIdx.x * 32;
  const int sm = tid >> 3;        // staging row 0..31
  const int sk = (tid & 7) << 2;  // staging k quad 0..28

  float4 ra, r1, r2;
  auto gload = [&](int kt) {
    ra = *(const float4*)(A + (m0 + sm) * 384 + kt + sk);
    r1 = *(const float4*)(W1 + (n0 + sm) * 384 + kt + sk);
    r2 = *(const float4*)(W2 + (n0 + sm) * 384 + kt + sk);
  };

  float a00 = 0.f, a01 = 0.f, a10 = 0.f, a11 = 0.f;
  float c00 = 0.f, c01 = 0.f, c10 = 0.f, c11 = 0.f;

  gload(0);
  for (int cc = 0; cc < 12; ++cc) {
    const int buf = cc & 1;
    // LDS write from regs loaded one full iteration ago (transpose to k-major)
    As[buf][sk + 0][sm] = ra.x; As[buf][sk + 1][sm] = ra.y;
    As[buf][sk + 2][sm] = ra.z; As[buf][sk + 3][sm] = ra.w;
    W1s[buf][sk + 0][sm] = r1.x; W1s[buf][sk + 1][sm] = r1.y;
    W1s[buf][sk + 2][sm] = r1.z; W1s[buf][sk + 3][sm] = r1.w;
    W2s[buf][sk + 0][sm] = r2.x; W2s[buf][sk + 1][sm] = r2.y;
    W2s[buf][sk + 2][sm] = r2.z; W2s[buf][sk + 3][sm] = r2.w;
    if (cc + 1 < 12) gload((cc + 1) * 32);  // in flight across the compute
    __syncthreads();  // publish buf; everyone done reading buf^1 (chunk cc-1)
#pragma unroll
    for (int k = 0; k < 32; ++k) {
      const float2 av = *(const float2*)&As[buf][k][2 * ty];
      const float2 w1 = *(const float2*)&W1s[buf][k][2 * tx];
      const float2 w2 = *(const float2*)&W2s[buf][k][2 * tx];
      a00 = fmaf(av.x, w1.x, a00); a01 = fmaf(av.x, w1.y, a01);
      a10 = fmaf(av.y, w1.x, a10); a11 = fmaf(av.y, w1.y, a11);
      c00 = fmaf(av.x, w2.x, c00); c01 = fmaf(av.x, w2.y, c01);
      c10 = fmaf(av.y, w2.x, c10); c11 = fmaf(av.y, w2.y, c11);
    }
  }

  const int r0 = m0 + 2 * ty, r1r = r0 + 1;
  const int q0 = n0 + 2 * tx;
  if constexpr (SP) {
    const float bb0 = b1[q0], bb1 = b1[q0 + 1];
    float2 o0 = {softplus_f(a00 + bb0), softplus_f(a01 + bb1)};
    float2 o1 = {softplus_f(a10 + bb0), softplus_f(a11 + bb1)};
    *(float2*)(O1 + r0 * 384 + q0) = o0;
    *(float2*)(O1 + r1r * 384 + q0) = o1;
  } else {
    float2 o0 = {a00, a01};
    float2 o1 = {a10, a11};
    *(float2*)(O1 + r0 * 384 + q0) = o0;
    *(float2*)(O1 + r1r * 384 + q0) = o1;
  }
  float2 p0 = {c00, c01};
  float2 p1 = {c10, c11};
  *(float2*)(O2 + r0 * 384 + q0) = p0;
  *(float2*)(O2 + r1r * 384 + q0) = p1;
}

// ---------------------------------------------------------------------------
// Causal depthwise conv (k=4, left pad 3) + bias + SiLU -> u[b,l,i]
// ---------------------------------------------------------------------------
__global__ __launch_bounds__(256) void conv_silu_kernel(
    const float* __restrict__ x, const float* __restrict__ cw,
    const float* __restrict__ cb, float* __restrict__ u) {
  const int idx = blockIdx.x * 256 + threadIdx.x;
  const int i = idx % D_SZ;
  const int l = (idx / D_SZ) % L_SZ;
  const int b = idx / BLK_ELEMS;
  float acc = cb[i];
#pragma unroll
  for (int t = 0; t < 4; t++) {
    const int ls = l - 3 + t;
    const float xv = (ls >= 0) ? x[(b * L_SZ + ls) * D_SZ + i] : 0.f;
    acc = fmaf(xv, cw[i * 4 + t], acc);
  }
  u[idx] = acc / (1.f + __expf(-acc));
}

// ---------------------------------------------------------------------------
// Selective scan v4: TLP via j-split. Each scan (b,i) is handled by 3
// INDEPENDENT waves (w=0,1,2), each owning 128 states (2 per lane,
// j = 128*w + 2*lane + e). No barriers, no cross-wave coupling: wave w
// writes its partial y (w=0 adds u*D) and a combine kernel sums them.
// 2304 waves (2.25/SIMD). Register ping-pong CH=8; launch_bounds(64,3)
// keeps ~85 VGPRs legal so the compiler does NOT sink the prefetch
// (R2's (64) default capped at 64 VGPR and serialized the pipeline).
// ---------------------------------------------------------------------------
#define CH 8
__global__ __launch_bounds__(64, 3) void scan_kernel(
    const float* __restrict__ A_log, const float* __restrict__ Dp,
    const float* __restrict__ dt, const float* __restrict__ Bm,
    const float* __restrict__ Cm, const float* __restrict__ u,
    float* __restrict__ y, float* __restrict__ p1, float* __restrict__ p2) {
  const int bid = blockIdx.x;   // 0..2303
  const int sid = bid / 3;
  const int w = bid % 3;
  const int b = sid / D_SZ;
  const int i = sid % D_SZ;
  const int lane = threadIdx.x;
  const int j0 = w * 128 + 2 * lane;

  const float2 av = *(const float2*)(A_log + i * S_SZ + j0);
  const float2 bv = *(const float2*)(Bm + (b * D_SZ + i) * S_SZ + j0);
  const float a20 = -__expf(av.x) * LOG2E;
  const float a21 = -__expf(av.y) * LOG2E;
  const float bw0 = bv.x, bw1 = bv.y;
  float h0 = 0.f, h1 = 0.f;
  const float Di = Dp[i];  // used only by w==0 (wave-uniform branch)

  const float* dtp = dt + b * BLK_ELEMS + i;
  const float* up = u + b * BLK_ELEMS + i;
  const float* cp = Cm + b * BLK_ELEMS + j0;
  float* yout = (w == 0) ? y : ((w == 1) ? p1 : p2);
  float* yp = yout + b * BLK_ELEMS + i;

  float cA[2 * CH], dA_[CH], uA[CH];
  float cB[2 * CH], dB_[CH], uB[CH];

  auto load_chunk = [&](int c, float (&cx)[2 * CH], float (&dx)[CH],
                        float (&ux)[CH]) {
    const int l0 = c * CH;
#pragma unroll
    for (int s = 0; s < CH; ++s) {
      dx[s] = dtp[(l0 + s) * D_SZ];
      ux[s] = up[(l0 + s) * D_SZ];
      const float2 c2 = *(const float2*)(cp + (l0 + s) * D_SZ);
      cx[2 * s] = c2.x;
      cx[2 * s + 1] = c2.y;
    }
  };

  auto compute_chunk = [&](int c, const float (&cx)[2 * CH],
                           const float (&dx)[CH], const float (&ux)[CH]) {
    const int l0 = c * CH;
    float accs[CH];
    // phase A: serial h-recurrence, per-lane partial dot
#pragma unroll
    for (int s = 0; s < CH; ++s) {
      const float dts = dx[s], us = ux[s];
      const float dtu = dts * us;
      const float e0 = fexp2(dts * a20);
      const float e1 = fexp2(dts * a21);
      h0 = fmaf(e0, h0, bw0 * dtu);
      h1 = fmaf(e1, h1, bw1 * dtu);
      accs[s] = fmaf(h1, cx[2 * s + 1], h0 * cx[2 * s]);
    }
    // phase B: 8 independent DPP chains (ILP hides DPP latency)
#pragma unroll
    for (int s = 0; s < CH; ++s) accs[s] = wave_reduce_lane63(accs[s]);
    if (lane == 63) {
#pragma unroll
      for (int s = 0; s < CH; ++s) {
        const float v = (w == 0) ? fmaf(ux[s], Di, accs[s]) : accs[s];
        yp[(l0 + s) * D_SZ] = v;
      }
    }
  };

  load_chunk(0, cA, dA_, uA);
  for (int it = 0; it < 24; ++it) {
    const int c0 = 2 * it;
    load_chunk(c0 + 1, cB, dB_, uB);
    compute_chunk(c0, cA, dA_, uA);
    const int cn = (c0 + 2 < 48) ? (c0 + 2) : 47;  // last prefetch harmless
    load_chunk(cn, cA, dA_, uA);
    compute_chunk(c0 + 1, cB, dB_, uB);
  }
}

// ---------------------------------------------------------------------------
// y += p1 + p2 (sum the j-split partials)
// ---------------------------------------------------------------------------
__global__ __launch_bounds__(256) void combine_kernel(
    float* __restrict__ y, const float* __restrict__ p1,
    const float* __restrict__ p2) {
  const int idx = blockIdx.x * 256 + threadIdx.x;  // float4 index
  float4 a = ((const float4*)y)[idx];
  const float4 b = ((const float4*)p1)[idx];
  const float4 c = ((const float4*)p2)[idx];
  a.x += b.x + c.x;
  a.y += b.y + c.y;
  a.z += b.z + c.z;
  a.w += b.w + c.w;
  ((float4*)y)[idx] = a;
}

extern "C" void kernel_launch(void* const* d_in, const int* in_sizes, int n_in,
                              void* d_out, int out_size, void* d_ws,
                              size_t ws_size, hipStream_t stream) {
  const float* x = (const float*)d_in[0];
  const float* A_log = (const float*)d_in[1];
  const float* D = (const float*)d_in[2];
  const float* dt_w = (const float*)d_in[3];
  const float* dt_b = (const float*)d_in[4];
  const float* B_w = (const float*)d_in[5];
  const float* C_w = (const float*)d_in[6];
  const float* conv_w = (const float*)d_in[7];
  const float* conv_b = (const float*)d_in[8];
  float* y = (float*)d_out;

  float* ws = (float*)d_ws;
  float* dt = ws;                    // slot 0
  float* xdbl = ws + TOT_ELEMS;      // slot 1 (reused as p1 after GEMM2)
  float* Bm = ws + 2 * TOT_ELEMS;    // slot 2
  float* Cm = ws + 3 * TOT_ELEMS;    // slot 3
  float* u = ws + 4 * TOT_ELEMS;     // slot 4
  float* p2 = ws + 5 * TOT_ELEMS;    // slot 5 (total 7.1 MB)
  float* p1 = xdbl;                  // xdbl dead after GEMM2

  const dim3 gemm_grid(D_SZ / 32, (B_SZ * L_SZ) / 32);  // 12 x 24 = 288
  dual_gemm_nt<true><<<gemm_grid, 256, 0, stream>>>(x, dt_w, B_w, dt_b, dt, xdbl);
  dual_gemm_nt<false><<<gemm_grid, 256, 0, stream>>>(xdbl, B_w, C_w, nullptr, Bm, Cm);
  conv_silu_kernel<<<TOT_ELEMS / 256, 256, 0, stream>>>(x, conv_w, conv_b, u);
  scan_kernel<<<3 * B_SZ * D_SZ, 64, 0, stream>>>(A_log, D, dt, Bm, Cm, u, y, p1, p2);
  combine_kernel<<<TOT_ELEMS / 4 / 256, 256, 0, stream>>>(y, p1, p2);
}